// Round 6
// baseline (219.323 us; speedup 1.0000x reference)
//
#include <hip/hip_runtime.h>

// Problem constants: B=16, DIM(C)=512, N=4096, H=8, HD=64, QKV rows = 8*129 = 1032.
#define NB 16
#define NC 512
#define NN 4096
#define NH 8

typedef __attribute__((ext_vector_type(8))) __bf16 bf16x8;
typedef __attribute__((ext_vector_type(4))) float f32x4;

__device__ __forceinline__ unsigned short f2bf(float f) {
    union { float f; unsigned u; } x; x.f = f;
    unsigned r = x.u + 0x7FFF + ((x.u >> 16) & 1);   // round-to-nearest-even
    return (unsigned short)(r >> 16);
}
__device__ __forceinline__ float bits2f(unsigned u) {
    union { unsigned u; float f; } x; x.u = u; return x.f;
}

// async global->LDS 16B per lane; LDS dest must be wave-uniform base (HW adds lane*16).
__device__ __forceinline__ void async16(const void* g, const void* l) {
    __builtin_amdgcn_global_load_lds(
        (const __attribute__((address_space(1))) void*)g,
        (__attribute__((address_space(3))) void*)l, 16, 0, 0);
}

// K0: repack Wv rows (head-interleaved) + Wp to bf16, gather bv.
__global__ void pack_kernel(const float* __restrict__ Wqkv, const float* __restrict__ bqkv,
                            const float* __restrict__ Wp,
                            unsigned short* __restrict__ Wv_bf, unsigned short* __restrict__ Wp_bf,
                            float* __restrict__ bv) {
    int t = blockIdx.x * 256 + threadIdx.x;          // 0 .. 512*512-1
    int j = t >> 9, c = t & 511;
    int h = j >> 6, d = j & 63;
    Wv_bf[t] = f2bf(Wqkv[((size_t)h * 129 + 65 + d) * 512 + c]);
    Wp_bf[t] = f2bf(Wp[t]);
    if (t < 512) bv[t] = bqkv[(t >> 6) * 129 + 65 + (t & 63)];
}

// K1: stream x natively: emit xbf (bf16 narrowing, native [b][c][n] layout, u32-packed)
// and q c-chunk partials qP[cc][b][h][n] (fp32 exact; bias dropped: softmax shift-inv).
// Block: 64 c x 512 n. Thread owns an n-pair. Grid (8 n-chunks, 8 c-chunks, 16 b).
__global__ __launch_bounds__(256) void q_xbf_kernel(
        const float* __restrict__ x, const float* __restrict__ Wqkv,
        unsigned int* __restrict__ xbf, float* __restrict__ qP) {
    __shared__ float Ws[8][64];
    int n0 = blockIdx.x * 512, c0 = blockIdx.y * 64, b = blockIdx.z;
    int t = threadIdx.x;                             // 256
    for (int i = t; i < 512; i += 256)
        Ws[i >> 6][i & 63] = Wqkv[(size_t)(i >> 6) * (129 * 512) + c0 + (i & 63)];
    __syncthreads();

    float acc[8][2];
#pragma unroll
    for (int h = 0; h < 8; h++) { acc[h][0] = 0.f; acc[h][1] = 0.f; }

    const float* xb = x + ((size_t)b * NC + c0) * NN + n0;
    unsigned int* ob = xbf + (((size_t)b * NC + c0) * NN + n0) / 2 + t;

#pragma unroll 4
    for (int c = 0; c < 64; c++) {
        float2 v = *((const float2*)(xb + (size_t)c * NN) + t);
        ob[(size_t)c * (NN / 2)] = (unsigned)f2bf(v.x) | ((unsigned)f2bf(v.y) << 16);
#pragma unroll
        for (int h = 0; h < 8; h++) {
            float w = Ws[h][c];
            acc[h][0] += w * v.x;
            acc[h][1] += w * v.y;
        }
    }
#pragma unroll
    for (int h = 0; h < 8; h++) {
        float2 o; o.x = acc[h][0]; o.y = acc[h][1];
        *((float2*)(qP + ((size_t)(blockIdx.y * NB + b) * 8 + h) * NN + n0) + t) = o;
    }
}

// K2: softmax over N per (b,h) of q = sum of 8 c-chunk partials.
// Writes TRANSPOSED scores sT[b][n][h] (fp32).
__global__ void softmax_kernel(const float* __restrict__ qP, float* __restrict__ sT) {
    int bh = blockIdx.x;                 // b*8+h
    int b = bh >> 3, h = bh & 7;
    int t = threadIdx.x;                 // 256
    __shared__ float red[8];
    const float* qp = qP + (size_t)bh * NN;
    const size_t cstr = (size_t)NB * 8 * NN;         // c-chunk stride in qP
    float v[16];
    float mx = -1e30f;
#pragma unroll
    for (int i = 0; i < 16; i++) {
        int n = t + i * 256;
        float s = 0.f;
#pragma unroll
        for (int cb = 0; cb < 8; cb++) s += qp[cb * cstr + n];
        v[i] = s; mx = fmaxf(mx, s);
    }
#pragma unroll
    for (int o = 32; o; o >>= 1) mx = fmaxf(mx, __shfl_xor(mx, o));
    if ((t & 63) == 0) red[t >> 6] = mx;
    __syncthreads();
    mx = fmaxf(fmaxf(red[0], red[1]), fmaxf(red[2], red[3]));
    float s = 0.f;
#pragma unroll
    for (int i = 0; i < 16; i++) { v[i] = __expf(v[i] - mx); s += v[i]; }
#pragma unroll
    for (int o = 32; o; o >>= 1) s += __shfl_xor(s, o);
    __syncthreads();
    if ((t & 63) == 0) red[4 + (t >> 6)] = s;
    __syncthreads();
    float inv = 1.f / (red[4] + red[5] + red[6] + red[7]);
#pragma unroll
    for (int i = 0; i < 16; i++) {
        int n = t + i * 256;
        sT[((size_t)b * NN + n) * 8 + h] = v[i] * inv;
    }
}

// K3: partial xbar[slab][b][h][c] = sum_{n in 512-slab} sT[b][n][h] * x[b,c,n]  (from xbf)
// Block: 32 c x 512 n, 4 waves; wave owns 8 c-rows; lane owns 8 consecutive n.
__global__ __launch_bounds__(256) void xbar_kernel(
        const unsigned int* __restrict__ xbf, const float* __restrict__ sT,
        float* __restrict__ xbarP) {
    __shared__ float red[4][8][64];
    int c0 = blockIdx.x * 32, sl = blockIdx.y, b = blockIdx.z;
    int t = threadIdx.x;
    int l = t & 63, w = t >> 6;
    int nsl0 = sl * 512;
    // s in registers: s_[j][h] for this lane's 8 n
    float s_[8][8];
    {
        const f32x4* sp = (const f32x4*)(sT + ((size_t)b * NN + nsl0 + l * 8) * 8);
#pragma unroll
        for (int j = 0; j < 8; j++) {
            f32x4 a = sp[2 * j], bq = sp[2 * j + 1];
            s_[j][0] = a[0]; s_[j][1] = a[1]; s_[j][2] = a[2]; s_[j][3] = a[3];
            s_[j][4] = bq[0]; s_[j][5] = bq[1]; s_[j][6] = bq[2]; s_[j][7] = bq[3];
        }
    }
    float acc[8][8];
#pragma unroll
    for (int r = 0; r < 8; r++)
#pragma unroll
        for (int h = 0; h < 8; h++) acc[r][h] = 0.f;

    const unsigned int* xr = xbf + (((size_t)b * NC + c0 + w * 8) * NN + nsl0) / 2 + l * 4;
    uint4 xv = *(const uint4*)(xr);
#pragma unroll
    for (int r = 0; r < 8; r++) {
        uint4 cur = xv;
        if (r < 7) xv = *(const uint4*)(xr + (size_t)(r + 1) * (NN / 2));
        float xf[8];
        xf[0] = bits2f(cur.x << 16); xf[1] = bits2f(cur.x & 0xFFFF0000u);
        xf[2] = bits2f(cur.y << 16); xf[3] = bits2f(cur.y & 0xFFFF0000u);
        xf[4] = bits2f(cur.z << 16); xf[5] = bits2f(cur.z & 0xFFFF0000u);
        xf[6] = bits2f(cur.w << 16); xf[7] = bits2f(cur.w & 0xFFFF0000u);
#pragma unroll
        for (int j = 0; j < 8; j++)
#pragma unroll
            for (int h = 0; h < 8; h++) acc[r][h] += xf[j] * s_[j][h];
    }
    // fold across the 8 lanes sharing (l&7): residue-class sums
#pragma unroll
    for (int r = 0; r < 8; r++)
#pragma unroll
        for (int h = 0; h < 8; h++) {
            float a = acc[r][h];
            a += __shfl_xor(a, 8);
            a += __shfl_xor(a, 16);
            a += __shfl_xor(a, 32);
            acc[r][h] = a;
        }
    if (l < 8) {
#pragma unroll
        for (int r = 0; r < 8; r++)
#pragma unroll
            for (int h = 0; h < 8; h++) red[w][l][r * 8 + h] = acc[r][h];
    }
    __syncthreads();
    {
        int idx = t & 63;                            // (r = idx>>3, h = idx&7)
        float v = 0.f;
#pragma unroll
        for (int res = 0; res < 8; res++) v += red[w][res][idx];
        int r = idx >> 3, h = idx & 7;
        xbarP[(((size_t)sl * NB + b) * 8 + h) * NC + c0 + w * 8 + r] = v;
    }
}

// K4: ctx[b][h*64+d] = Wk[h,d,:].xbar[b,h,:] + bk[h,d]   (sums 8 partial slabs)
__global__ void ctx_kernel(const float* __restrict__ xbarP, const float* __restrict__ Wqkv,
                           const float* __restrict__ bqkv, float* __restrict__ ctx) {
    int bh = blockIdx.x; int b = bh >> 3, h = bh & 7;
    int t = threadIdx.x;                                    // 256
    __shared__ float xb[512];
    for (int i = t; i < 512; i += 256) {
        float s = 0.f;
#pragma unroll
        for (int sl = 0; sl < 8; sl++) s += xbarP[(((size_t)sl * NB + b) * 8 + h) * NC + i];
        xb[i] = s;
    }
    __syncthreads();
    int d = t >> 2, sub = t & 3;
    const float* wk = Wqkv + ((size_t)h * 129 + 1 + d) * 512;
    float acc = 0.f;
    for (int i = sub * 4; i < 512; i += 16) {
        float4 w = *(const float4*)(wk + i);
        acc += w.x * xb[i] + w.y * xb[i + 1] + w.z * xb[i + 2] + w.w * xb[i + 3];
    }
    acc += __shfl_xor(acc, 1);
    acc += __shfl_xor(acc, 2);
    if (sub == 0) ctx[(size_t)b * NC + h * 64 + d] = acc + bqkv[h * 129 + 1 + d];
}

// K5/K6: C[512 x 4096] = A[512x512] * B, per batch.
// MODE 0: B = xbf native [c][n] (u32-packed bf16); in-kernel transpose staging with
//         XOR-swizzled LDS writes. Epilogue relu(acc+bv)*ctx -> bf16 TRANSPOSED mT[b][n][j].
// MODE 1: B = mT [n][k] bf16 rows, async16 staging. Epilogue acc+bp -> fp32 out[b][o][n].
template <int MODE>
__global__ __launch_bounds__(512) void gemm_kernel(
    const unsigned short* __restrict__ A,     // [512][512] bf16 row-major
    const unsigned short* __restrict__ Bmat,  // MODE0: xbf u32-packed; MODE1: mT
    const float* __restrict__ bias,           // bv or bp
    const float* __restrict__ ctx,            // [B][512] (MODE 0)
    unsigned short* __restrict__ mT,          // MODE 0 output
    float* __restrict__ outp)                 // MODE 1 output
{
    __shared__ alignas(16) unsigned short As[256 * 32];   // [m][k] linear (async dest)
    __shared__ alignas(16) unsigned short Bs[128 * 32];   // [n][k], MODE0: XOR-swizzled
    int b = blockIdx.z;
    int m0 = blockIdx.y * 256, n0 = blockIdx.x * 128;
    int t = threadIdx.x;
    int lane = t & 63;
    int wid = t >> 6;                                     // 8 waves
    int wm = wid >> 1, wn = wid & 1;                      // 4x2 wave grid, 64x64 per wave

    const unsigned short* Bb = Bmat + ((size_t)b * NN + n0) * NC;          // MODE1
    const unsigned int*   Bu = (const unsigned int*)Bmat + (size_t)b * NC * (NN / 2); // MODE0

    // per-lane source offsets for async staging (16B each; dest = wave base + lane*16)
    int srow = lane >> 2, sc8 = (lane & 3) * 8;

    f32x4 acc[4][4];
#pragma unroll
    for (int i = 0; i < 4; i++)
#pragma unroll
        for (int j = 0; j < 4; j++) { f32x4 z = {0.f, 0.f, 0.f, 0.f}; acc[i][j] = z; }

    for (int kk = 0; kk < 512; kk += 32) {
        // A rows [wid*32, wid*32+32): two 1KB async chunks.
        async16(A + (size_t)(m0 + wid * 32 + srow) * 512 + kk + sc8,      As + wid * 1024);
        async16(A + (size_t)(m0 + wid * 32 + 16 + srow) * 512 + kk + sc8, As + wid * 1024 + 512);
        if constexpr (MODE == 0) {
            // B from native xbf: thread t stages row c = t>>4, n = n0 + (t&15)*8 .. +7.
            int c = t >> 4, nb = (t & 15) * 8;
            uint4 xv = *(const uint4*)(Bu + ((size_t)(kk + c) * NN + n0 + nb) / 2);
            const unsigned short* xp16 = (const unsigned short*)&xv;
#pragma unroll
            for (int i = 0; i < 8; i++) {
                int nl = nb + i;
                int byte = nl * 64 + ((c * 2) ^ (((nl >> 3) & 3) << 4));
                *(unsigned short*)((char*)Bs + byte) = xp16[i];
            }
        } else {
            async16(Bb + (size_t)(wid * 16 + srow) * 512 + kk + sc8, Bs + wid * 512);
        }
        __syncthreads();                                  // drains vmcnt+lgkmcnt
        bf16x8 af[4], bfr[4];
        int koff = (lane >> 4) * 8;
        int arow = wm * 64 + (lane & 15);
        int brow = wn * 64 + (lane & 15);
#pragma unroll
        for (int i = 0; i < 4; i++) af[i]  = *(const bf16x8*)(As + (size_t)(arow + i * 16) * 32 + koff);
#pragma unroll
        for (int j = 0; j < 4; j++) {
            if constexpr (MODE == 0) {
                int row = brow + j * 16;
                int byte = row * 64 + ((koff * 2) ^ (((row >> 3) & 3) << 4));
                bfr[j] = *(const bf16x8*)((const char*)Bs + byte);
            } else {
                bfr[j] = *(const bf16x8*)(Bs + (size_t)(brow + j * 16) * 32 + koff);
            }
        }
#pragma unroll
        for (int i = 0; i < 4; i++)
#pragma unroll
            for (int j = 0; j < 4; j++)
                acc[i][j] = __builtin_amdgcn_mfma_f32_16x16x32_bf16(af[i], bfr[j], acc[i][j], 0, 0, 0);
        __syncthreads();
    }

    // epilogue; D frag: col = lane&15, row = (lane>>4)*4 + reg
    int g = lane >> 4, col = lane & 15;
#pragma unroll
    for (int i = 0; i < 4; i++) {
        int j0 = m0 + wm * 64 + i * 16 + g * 4;           // 4 consecutive output rows
        if (MODE == 0) {
            float4 bv4 = *(const float4*)(bias + j0);
            float4 cx4 = *(const float4*)(ctx + (size_t)b * NC + j0);
#pragma unroll
            for (int j = 0; j < 4; j++) {
                int n = n0 + wn * 64 + j * 16 + col;
                f32x4 a = acc[i][j];
                unsigned short h0 = f2bf(fmaxf(a[0] + bv4.x, 0.f) * cx4.x);
                unsigned short h1 = f2bf(fmaxf(a[1] + bv4.y, 0.f) * cx4.y);
                unsigned short h2 = f2bf(fmaxf(a[2] + bv4.z, 0.f) * cx4.z);
                unsigned short h3 = f2bf(fmaxf(a[3] + bv4.w, 0.f) * cx4.w);
                uint2 pk;
                pk.x = (unsigned)h0 | ((unsigned)h1 << 16);
                pk.y = (unsigned)h2 | ((unsigned)h3 << 16);
                *(uint2*)(mT + ((size_t)b * NN + n) * NC + j0) = pk;
            }
        } else {
            float4 bp4 = *(const float4*)(bias + j0);
#pragma unroll
            for (int j = 0; j < 4; j++) {
                int n = n0 + wn * 64 + j * 16 + col;
                f32x4 a = acc[i][j];
                float* op = outp + (size_t)b * NC * NN + (size_t)j0 * NN + n;
                op[0]              = a[0] + bp4.x;
                op[NN]             = a[1] + bp4.y;
                op[2 * (size_t)NN] = a[2] + bp4.z;
                op[3 * (size_t)NN] = a[3] + bp4.w;
            }
        }
    }
}

extern "C" void kernel_launch(void* const* d_in, const int* in_sizes, int n_in,
                              void* d_out, int out_size, void* d_ws, size_t ws_size,
                              hipStream_t stream) {
    const float* x    = (const float*)d_in[0];
    const float* Wqkv = (const float*)d_in[1];
    const float* bqkv = (const float*)d_in[2];
    const float* Wp   = (const float*)d_in[3];
    const float* bp   = (const float*)d_in[4];
    float* outp = (float*)d_out;

    // ws layout. mT occupies [0, 64MB). sT/qP/xbarP overlap mT's range but are
    // fully consumed (K1..K4) before K5 writes mT. ctx/Wv/Wp/bv live past 64MB.
    char* ws = (char*)d_ws;
    unsigned short* mT = (unsigned short*)ws;                         // 64 MB
    float* sT    = (float*)(ws + 2097152);                            // [2MB,4MB)
    float* qP    = (float*)(ws + 4194304);                            // [4MB,20MB)
    float* xbarP = (float*)(ws + 20971520);                           // [20MB,22MB)
    float* ctx   = (float*)(ws + 67108864);                           // 32 KB
    unsigned short* Wv_bf = (unsigned short*)(ws + 67108864 + 32768);            // 512 KB
    unsigned short* Wp_bf = (unsigned short*)(ws + 67108864 + 32768 + 524288);   // 512 KB
    float* bv    = (float*)(ws + 67108864 + 32768 + 1048576);         // 2 KB
    // xbf (bf16 native-layout x, u32-packed, 64MB) lives in d_out's first half;
    // it is dead before K6 overwrites all of d_out.
    unsigned int* xbf = (unsigned int*)d_out;

    pack_kernel<<<dim3(1024), 256, 0, stream>>>(Wqkv, bqkv, Wp, Wv_bf, Wp_bf, bv);
    q_xbf_kernel<<<dim3(8, 8, 16), 256, 0, stream>>>(x, Wqkv, xbf, qP);
    softmax_kernel<<<dim3(128), 256, 0, stream>>>(qP, sT);
    xbar_kernel<<<dim3(16, 8, 16), 256, 0, stream>>>(xbf, sT, xbarP);
    ctx_kernel<<<dim3(128), 256, 0, stream>>>(xbarP, Wqkv, bqkv, ctx);
    gemm_kernel<0><<<dim3(32, 2, 16), 512, 0, stream>>>(
        Wv_bf, (const unsigned short*)xbf, bv, ctx, mT, nullptr);
    gemm_kernel<1><<<dim3(32, 2, 16), 512, 0, stream>>>(
        Wp_bf, mT, bp, nullptr, nullptr, outp);
}